// Round 4
// baseline (1737.487 us; speedup 1.0000x reference)
//
#include <hip/hip_runtime.h>
#include <math.h>

// EM routing (DigitCaps) B=16, N=16384, C=10, D=16, ITER_ROUTING=3.
// One votes pass per iteration accumulating unnormalized moments
// sum(r), sum(r*v), sum(r*v^2) per (b,c,d); tiny finalize kernels between.
// sigma via moment identity (no extra pass). Final act_out (beta_v/beta_a)
// does not affect returned miu -> skipped.
//
// R3 lesson: local float arrays passed by pointer into reduce_tail() were
// demoted to scratch (VGPR_Count=64, 82 MB WRITE_SIZE of spill traffic,
// VALUBusy 3%). Fix: all per-thread state is ext_vector_type (SSA, never
// address-taken), reductions inlined with constant indices.

typedef float f32x16 __attribute__((ext_vector_type(16)));

namespace {
constexpr int BB = 16;
constexpr int NN = 16384;
constexpr int CC = 10;
constexpr int DD = 16;
constexpr float EPSF = 1e-9f;
constexpr int CHUNKS = 128;                  // blocks per batch b
constexpr int ROWS_PER_CHUNK = NN / CHUNKS;  // 128 rows per block
// workspace (float) layout
constexpr int ACC_SZ = BB * CC * DD * 2 + BB * CC;  // rv | rv2 | rsum = 5280
constexpr int RV_OFF = 0;
constexpr int RV2_OFF = BB * CC * DD;               // 2560
constexpr int RS_OFF = 2 * BB * CC * DD;            // 5120
constexpr int PAR_BASE = 3 * ACC_SZ;                // 15840 (64B-aligned: 15840*4%64==0)
constexpr int PAR_SZ = 3 * BB * CC * DD + BB * CC;  // miu | A | i2s | act = 7840
constexpr int PMIU = 0;
constexpr int PA = BB * CC * DD;
constexpr int PI2S = 2 * BB * CC * DD;
constexpr int PACT = 3 * BB * CC * DD;
constexpr float LOG10x16 = 36.841361487904734f;     // 16*ln(10)
}  // namespace

__global__ void zero_acc(float* ws) {
  int i = blockIdx.x * blockDim.x + threadIdx.x;
  if (i < 3 * ACC_SZ) ws[i] = 0.0f;
}

__global__ __launch_bounds__(256, 2) void pass0(const float* __restrict__ votes,
                                                const float* __restrict__ activ,
                                                float* __restrict__ acc) {
  const int b = blockIdx.x / CHUNKS;
  const int chunk = blockIdx.x % CHUNKS;
  const int tid = threadIdx.x;
  const int rslot = tid >> 4;
  const int c = tid & 15;
  const bool active = c < CC;
  f32x16 arv = {};
  f32x16 arv2 = {};
  float ar = 0.0f;
  const int n0 = chunk * ROWS_PER_CHUNK;
  for (int rr = rslot; rr < ROWS_PER_CHUNK; rr += 16) {
    const int n = n0 + rr;
    const float a = activ[b * NN + n];
    // r = (a/C) / (sum_c a/C + EPS) = (a/C)/(a + EPS)
    const float r = (a * (1.0f / CC)) / (a + EPSF);
    if (active) {
      const f32x16 v = *reinterpret_cast<const f32x16*>(
          votes + ((size_t)b * NN + n) * (CC * DD) + c * DD);
      const f32x16 t = r * v;
      arv += t;
      arv2 += t * v;
      ar += r;
    }
  }
  // wave merge of the 4 row-slots sharing each c
#pragma unroll
  for (int d = 0; d < DD; ++d) {
    float x = arv[d];
    x += __shfl_down(x, 32);
    x += __shfl_down(x, 16);
    arv[d] = x;
    float y = arv2[d];
    y += __shfl_down(y, 32);
    y += __shfl_down(y, 16);
    arv2[d] = y;
  }
  ar += __shfl_down(ar, 32);
  ar += __shfl_down(ar, 16);
  if ((tid & 63) < 16 && active) {
    float* rv = acc + RV_OFF + (b * CC + c) * DD;
    float* rv2 = acc + RV2_OFF + (b * CC + c) * DD;
#pragma unroll
    for (int d = 0; d < DD; ++d) {
      atomicAdd(&rv[d], arv[d]);
      atomicAdd(&rv2[d], arv2[d]);
    }
    atomicAdd(&acc[RS_OFF + b * CC + c], ar);
  }
}

// IT = 1: accumulate rv, rv2, rsum.  IT = 2: rv, rsum only.
template <int IT>
__global__ __launch_bounds__(256, 2) void pass12(const float* __restrict__ votes,
                                                 const float* __restrict__ activ,
                                                 const float* __restrict__ par,
                                                 float* __restrict__ acc) {
  const int b = blockIdx.x / CHUNKS;
  const int chunk = blockIdx.x % CHUNKS;
  const int tid = threadIdx.x;
  const int rslot = tid >> 4;
  const int c = tid & 15;
  const bool active = c < CC;
  f32x16 miu = {}, Acv = {}, i2s = {};
  float actc = 0.0f;
  if (active) {
    const int pidx = (b * CC + c) * DD;
    miu = *reinterpret_cast<const f32x16*>(par + PMIU + pidx);
    Acv = *reinterpret_cast<const f32x16*>(par + PA + pidx);
    i2s = *reinterpret_cast<const f32x16*>(par + PI2S + pidx);
    actc = par[PACT + b * CC + c];
  }
  f32x16 arv = {};
  f32x16 arv2 = {};
  float ar = 0.0f;
  const int n0 = chunk * ROWS_PER_CHUNK;
  for (int rr = rslot; rr < ROWS_PER_CHUNK; rr += 16) {
    const int n = n0 + rr;
    f32x16 v = {};
    float s = 0.0f, mx = -INFINITY;
    if (active) {
      v = *reinterpret_cast<const f32x16*>(
          votes + ((size_t)b * NN + n) * (CC * DD) + c * DD);
      const f32x16 dv = v - miu;
      const f32x16 lp = Acv - dv * dv * i2s;
#pragma unroll
      for (int d = 0; d < DD; ++d) {
        s += lp[d];
        mx = fmaxf(mx, lp[d]);
      }
    }
    // max of log_p over (c,d) within the 16-lane c-group
    float M = mx;
    M = fmaxf(M, __shfl_xor(M, 1));
    M = fmaxf(M, __shfl_xor(M, 2));
    M = fmaxf(M, __shfl_xor(M, 4));
    M = fmaxf(M, __shfl_xor(M, 8));
    const float p = active ? expf(s - 16.0f * M + LOG10x16) : 0.0f;
    const float ap = p * actc;
    float sap = ap;
    sap += __shfl_xor(sap, 1);
    sap += __shfl_xor(sap, 2);
    sap += __shfl_xor(sap, 4);
    sap += __shfl_xor(sap, 8);
    const float a = activ[b * NN + n];
    float r = (ap / (sap + EPSF)) * a;
    // sum_c r = a * sap/(sap+EPS) in closed form
    const float sr = a * (sap / (sap + EPSF));
    r = r / (sr + EPSF);
    if (active) {
      ar += r;
      const f32x16 t = r * v;
      arv += t;
      if (IT == 1) arv2 += t * v;
    }
  }
#pragma unroll
  for (int d = 0; d < DD; ++d) {
    float x = arv[d];
    x += __shfl_down(x, 32);
    x += __shfl_down(x, 16);
    arv[d] = x;
    if (IT == 1) {
      float y = arv2[d];
      y += __shfl_down(y, 32);
      y += __shfl_down(y, 16);
      arv2[d] = y;
    }
  }
  ar += __shfl_down(ar, 32);
  ar += __shfl_down(ar, 16);
  if ((tid & 63) < 16 && active) {
    float* rv = acc + RV_OFF + (b * CC + c) * DD;
#pragma unroll
    for (int d = 0; d < DD; ++d) atomicAdd(&rv[d], arv[d]);
    if (IT == 1) {
      float* rv2 = acc + RV2_OFF + (b * CC + c) * DD;
#pragma unroll
      for (int d = 0; d < DD; ++d) atomicAdd(&rv2[d], arv2[d]);
    }
    atomicAdd(&acc[RS_OFF + b * CC + c], ar);
  }
}

// Computes miu (and, unless FINAL, A=-0.5*ln(sigma), 1/(2*sigma), act=softmax(rsum)).
template <bool FINAL>
__global__ void finalize_k(const float* __restrict__ acc, float* __restrict__ par_out,
                           float* __restrict__ out) {
  const int idx = blockIdx.x * blockDim.x + threadIdx.x;
  if (idx < BB * CC * DD) {
    const int bc = idx / DD;
    const float rs = acc[RS_OFF + bc];
    const float den = rs + EPSF;
    const float miu = acc[RV_OFF + idx] / den;
    if (FINAL) {
      out[idx] = miu;
    } else {
      const float rv2 = acc[RV2_OFF + idx];
      const float S = rs / den;
      const float sig = rv2 / den - miu * miu * (2.0f - S) + EPSF;
      par_out[PMIU + idx] = miu;
      par_out[PA + idx] = -0.5f * logf(sig);
      par_out[PI2S + idx] = 0.5f / sig;
    }
  }
  if (!FINAL && blockIdx.x == 0 && threadIdx.x < BB) {
    const int b = threadIdx.x;
    float rsv[CC], e[CC];
    float m = -INFINITY;
    for (int c = 0; c < CC; ++c) {
      rsv[c] = acc[RS_OFF + b * CC + c];
      m = fmaxf(m, rsv[c]);
    }
    float ss = 0.0f;
    for (int c = 0; c < CC; ++c) {
      e[c] = expf(rsv[c] - m);
      ss += e[c];
    }
    for (int c = 0; c < CC; ++c) par_out[PACT + b * CC + c] = e[c] / ss;
  }
}

extern "C" void kernel_launch(void* const* d_in, const int* in_sizes, int n_in,
                              void* d_out, int out_size, void* d_ws, size_t ws_size,
                              hipStream_t stream) {
  const float* votes = (const float*)d_in[0];
  const float* activ = (const float*)d_in[1];
  // d_in[2] (beta_v) and d_in[3] (beta_a) only affect the final act_out,
  // which does not influence the returned miu -> unused.
  float* ws = (float*)d_ws;
  float* out = (float*)d_out;

  zero_acc<<<dim3((3 * ACC_SZ + 255) / 256), dim3(256), 0, stream>>>(ws);

  float* acc0 = ws;
  float* acc1 = ws + ACC_SZ;
  float* acc2 = ws + 2 * ACC_SZ;
  float* par0 = ws + PAR_BASE;
  float* par1 = ws + PAR_BASE + PAR_SZ;

  pass0<<<dim3(BB * CHUNKS), dim3(256), 0, stream>>>(votes, activ, acc0);
  finalize_k<false><<<dim3((BB * CC * DD + 255) / 256), dim3(256), 0, stream>>>(
      acc0, par0, nullptr);
  pass12<1><<<dim3(BB * CHUNKS), dim3(256), 0, stream>>>(votes, activ, par0, acc1);
  finalize_k<false><<<dim3((BB * CC * DD + 255) / 256), dim3(256), 0, stream>>>(
      acc1, par1, nullptr);
  pass12<2><<<dim3(BB * CHUNKS), dim3(256), 0, stream>>>(votes, activ, par1, acc2);
  finalize_k<true><<<dim3((BB * CC * DD + 255) / 256), dim3(256), 0, stream>>>(
      acc2, nullptr, out);
}

// Round 6
// 435.313 us; speedup vs baseline: 3.9913x; 3.9913x over previous
//
#include <hip/hip_runtime.h>
#include <math.h>

// EM routing (DigitCaps) B=16, N=16384, C=10, D=16, ITER_ROUTING=3.
// One votes pass per iteration accumulating sum(r), sum(r*v), sum(r*v^2)
// per (b,c,d) via wave-folded atomicAdd into tiny acc buffers; finalize
// kernels between passes. sigma via moment identity. Final act_out
// (beta_v/beta_a) never feeds returned miu -> skipped.
//
// R3 lesson: float arrays passed by pointer -> scratch spill (VGPR 64).
// R4 lesson: f32x16 ext_vectors also demoted (VGPR 36, 4x slower).
// R5 lesson: per-wave partial buffers (5.2 MiB) overflowed ws_size ->
//            stomped adjacent input buffer -> replays diverged. Fixed
//            footprint: 126 KB (R3-proven), atomics for accumulation.
// Per-thread state: named float4/scalars only (never address-taken).
//
// Thread map (256/block, 4 waves): lane = tid&63; rg = lane&31;
//   c = rg>>1 (c>=10 clamped+masked), half = rg&1 (owns d = 8h..8h+7),
//   row-slot = (lane>>5) + 2*wave -> 8 rows per block-step.

namespace {
constexpr int BB = 16, NN = 16384, CC = 10, DD = 16;
constexpr float EPSF = 1e-9f;
constexpr int CHUNKS = 64;                   // blocks per batch b
constexpr int ROWS = NN / CHUNKS;            // 256 rows per block
// acc buffer layout (floats)
constexpr int ACC_SZ = BB * CC * DD * 2 + BB * CC;  // rv | rv2 | rs = 5280
constexpr int RV_OFF = 0;
constexpr int RV2_OFF = BB * CC * DD;               // 2560
constexpr int RS_OFF = 2 * BB * CC * DD;            // 5120
constexpr int PAR_BASE = 3 * ACC_SZ;                // 15840 (x4B = 64B-aligned)
constexpr int PAR_SZ = 3 * BB * CC * DD + BB * CC;  // miu | A | i2s | act = 7840
constexpr int PMIU = 0;
constexpr int PA = BB * CC * DD;
constexpr int PI2S = 2 * BB * CC * DD;
constexpr int PACT = 3 * BB * CC * DD;
// total ws: 3*ACC_SZ + 2*PAR_SZ = 31520 floats = 126 KB (R3-proven fit)
}  // namespace

__global__ void zero_acc(float* ws) {
  int i = blockIdx.x * blockDim.x + threadIdx.x;
  if (i < 3 * ACC_SZ) ws[i] = 0.0f;
}

// IT=0: r from activation only. IT=1: EM step, writes rv,rv2,rs.
// IT=2: EM step, rv,rs only.
template <int IT>
__global__ __launch_bounds__(256) void pass_k(const float* __restrict__ votes,
                                              const float* __restrict__ activ,
                                              const float* __restrict__ par,
                                              float* __restrict__ acc) {
  const int b = blockIdx.x / CHUNKS;
  const int chunk = blockIdx.x - b * CHUNKS;
  const int tid = threadIdx.x;
  const int wave = tid >> 6;
  const int lane = tid & 63;
  const int rg = lane & 31;
  const int c = rg >> 1;
  const int half = rg & 1;
  const int cc = c < CC ? c : CC - 1;
  const bool on = c < CC;
  const int rslot = (lane >> 5) + wave * 2;  // 0..7

  float4 mi0 = make_float4(0.f, 0.f, 0.f, 0.f), mi1 = mi0;
  float4 A0 = mi0, A1 = mi0, is0 = mi0, is1 = mi0;
  float actc = 0.f;
  if (IT != 0) {
    const float* pb = par + (b * CC + cc) * DD + half * 8;
    mi0 = *(const float4*)(pb + PMIU);
    mi1 = *(const float4*)(pb + PMIU + 4);
    A0 = *(const float4*)(pb + PA);
    A1 = *(const float4*)(pb + PA + 4);
    is0 = *(const float4*)(pb + PI2S);
    is1 = *(const float4*)(pb + PI2S + 4);
    actc = par[PACT + b * CC + cc];
  }

  float4 rv0 = make_float4(0.f, 0.f, 0.f, 0.f), rv1 = rv0;
  float4 rw0 = rv0, rw1 = rv0;
  float ar = 0.f;

  const int n0 = chunk * ROWS;
  for (int k = rslot; k < ROWS; k += 8) {
    const int n = n0 + k;
    const float* vb = votes + (size_t)(b * NN + n) * (CC * DD) + cc * DD + half * 8;
    const float4 q0 = *(const float4*)vb;
    const float4 q1 = *(const float4*)(vb + 4);
    const float a = activ[b * NN + n];
    float r;
    if (IT == 0) {
      // r = (a/C)/(sum_c a/C + EPS) = (a/C)/(a+EPS); same for every c.
      r = (a * (1.0f / CC)) / (a + EPSF);
      ar += r;
    } else {
      float dx, s8 = 0.f;
      dx = q0.x - mi0.x; s8 += A0.x - dx * dx * is0.x;
      dx = q0.y - mi0.y; s8 += A0.y - dx * dx * is0.y;
      dx = q0.z - mi0.z; s8 += A0.z - dx * dx * is0.z;
      dx = q0.w - mi0.w; s8 += A0.w - dx * dx * is0.w;
      dx = q1.x - mi1.x; s8 += A1.x - dx * dx * is1.x;
      dx = q1.y - mi1.y; s8 += A1.y - dx * dx * is1.y;
      dx = q1.z - mi1.z; s8 += A1.z - dx * dx * is1.z;
      dx = q1.w - mi1.w; s8 += A1.w - dx * dx * is1.w;
      // S_c = sum_d log_p (pair merge); shift by max_c S (exact under ap/sum).
      const float S = s8 + __shfl_xor(s8, 1);
      float M = on ? S : -1e30f;
      M = fmaxf(M, __shfl_xor(M, 2));
      M = fmaxf(M, __shfl_xor(M, 4));
      M = fmaxf(M, __shfl_xor(M, 8));
      M = fmaxf(M, __shfl_xor(M, 16));
      const float te = on ? __expf(S - M) * actc : 0.f;
      float sap = te;  // sum over c: masks 2..16 never cross the half bit
      sap += __shfl_xor(sap, 2);
      sap += __shfl_xor(sap, 4);
      sap += __shfl_xor(sap, 8);
      sap += __shfl_xor(sap, 16);
      const float inv = 1.0f / (sap + EPSF);
      const float sr = a * sap * inv;  // = sum_c (ap/(sap+eps)*a)
      r = (te * inv * a) / (sr + EPSF);
      ar += r;
    }
    const float t0x = r * q0.x, t0y = r * q0.y, t0z = r * q0.z, t0w = r * q0.w;
    const float t1x = r * q1.x, t1y = r * q1.y, t1z = r * q1.z, t1w = r * q1.w;
    rv0.x += t0x; rv0.y += t0y; rv0.z += t0z; rv0.w += t0w;
    rv1.x += t1x; rv1.y += t1y; rv1.z += t1z; rv1.w += t1w;
    if (IT <= 1) {
      rw0.x += t0x * q0.x; rw0.y += t0y * q0.y; rw0.z += t0z * q0.z; rw0.w += t0w * q0.w;
      rw1.x += t1x * q1.x; rw1.y += t1y * q1.y; rw1.z += t1z * q1.z; rw1.w += t1w * q1.w;
    }
  }

  // fold the two row-slots of this wave (lane <-> lane+32)
  rv0.x += __shfl_down(rv0.x, 32); rv0.y += __shfl_down(rv0.y, 32);
  rv0.z += __shfl_down(rv0.z, 32); rv0.w += __shfl_down(rv0.w, 32);
  rv1.x += __shfl_down(rv1.x, 32); rv1.y += __shfl_down(rv1.y, 32);
  rv1.z += __shfl_down(rv1.z, 32); rv1.w += __shfl_down(rv1.w, 32);
  if (IT <= 1) {
    rw0.x += __shfl_down(rw0.x, 32); rw0.y += __shfl_down(rw0.y, 32);
    rw0.z += __shfl_down(rw0.z, 32); rw0.w += __shfl_down(rw0.w, 32);
    rw1.x += __shfl_down(rw1.x, 32); rw1.y += __shfl_down(rw1.y, 32);
    rw1.z += __shfl_down(rw1.z, 32); rw1.w += __shfl_down(rw1.w, 32);
  }
  ar += __shfl_down(ar, 32);

  if (lane < 32 && on) {
    float* rv = acc + RV_OFF + (b * CC + cc) * DD + half * 8;
    atomicAdd(&rv[0], rv0.x); atomicAdd(&rv[1], rv0.y);
    atomicAdd(&rv[2], rv0.z); atomicAdd(&rv[3], rv0.w);
    atomicAdd(&rv[4], rv1.x); atomicAdd(&rv[5], rv1.y);
    atomicAdd(&rv[6], rv1.z); atomicAdd(&rv[7], rv1.w);
    if (IT <= 1) {
      float* rw = acc + RV2_OFF + (b * CC + cc) * DD + half * 8;
      atomicAdd(&rw[0], rw0.x); atomicAdd(&rw[1], rw0.y);
      atomicAdd(&rw[2], rw0.z); atomicAdd(&rw[3], rw0.w);
      atomicAdd(&rw[4], rw1.x); atomicAdd(&rw[5], rw1.y);
      atomicAdd(&rw[6], rw1.z); atomicAdd(&rw[7], rw1.w);
    }
    if (half == 0) atomicAdd(&acc[RS_OFF + b * CC + cc], ar);
  }
}

// MODE=0: par_out = {miu, -0.5*ln(sig), 0.5/sig, act=softmax_c(rs)}.
// MODE=1: out = miu.
template <int MODE>
__global__ void finalize_k(const float* __restrict__ acc, float* __restrict__ par_out,
                           float* __restrict__ out) {
  const int idx = blockIdx.x * blockDim.x + threadIdx.x;
  if (idx < BB * CC * DD) {
    const int bc = idx / DD;
    const float rs = acc[RS_OFF + bc];
    const float den = rs + EPSF;
    const float miu = acc[RV_OFF + idx] / den;
    if (MODE == 1) {
      out[idx] = miu;
    } else {
      const float rv2 = acc[RV2_OFF + idx];
      const float Sf = rs / den;
      const float sig = rv2 / den - miu * miu * (2.0f - Sf) + EPSF;
      par_out[PMIU + idx] = miu;
      par_out[PA + idx] = -0.5f * logf(sig);
      par_out[PI2S + idx] = 0.5f / sig;
    }
  }
  if (MODE == 0 && blockIdx.x == 0 && threadIdx.x < BB) {
    const int b = threadIdx.x;
    float m = -1e30f;
    for (int i = 0; i < CC; ++i) m = fmaxf(m, acc[RS_OFF + b * CC + i]);
    float ss = 0.f;
    for (int i = 0; i < CC; ++i) ss += __expf(acc[RS_OFF + b * CC + i] - m);
    for (int i = 0; i < CC; ++i)
      par_out[PACT + b * CC + i] = __expf(acc[RS_OFF + b * CC + i] - m) / ss;
  }
}

extern "C" void kernel_launch(void* const* d_in, const int* in_sizes, int n_in,
                              void* d_out, int out_size, void* d_ws, size_t ws_size,
                              hipStream_t stream) {
  const float* votes = (const float*)d_in[0];
  const float* activ = (const float*)d_in[1];
  // d_in[2]/d_in[3] (beta_v, beta_a) only affect the post-final act_out,
  // which never feeds the returned miu -> unused.
  float* ws = (float*)d_ws;
  float* out = (float*)d_out;

  float* acc0 = ws;
  float* acc1 = ws + ACC_SZ;
  float* acc2 = ws + 2 * ACC_SZ;
  float* par0 = ws + PAR_BASE;
  float* par1 = ws + PAR_BASE + PAR_SZ;

  zero_acc<<<dim3((3 * ACC_SZ + 255) / 256), dim3(256), 0, stream>>>(ws);

  const dim3 gp(BB * CHUNKS), bp(256);
  const dim3 gf((BB * CC * DD + 255) / 256), bf(256);
  pass_k<0><<<gp, bp, 0, stream>>>(votes, activ, nullptr, acc0);
  finalize_k<0><<<gf, bf, 0, stream>>>(acc0, par0, nullptr);
  pass_k<1><<<gp, bp, 0, stream>>>(votes, activ, par0, acc1);
  finalize_k<0><<<gf, bf, 0, stream>>>(acc1, par1, nullptr);
  pass_k<2><<<gp, bp, 0, stream>>>(votes, activ, par1, acc2);
  finalize_k<1><<<gf, bf, 0, stream>>>(acc2, nullptr, out);
}